// Round 7
// baseline (38189.355 us; speedup 1.0000x reference)
//
#include <hip/hip_runtime.h>
#include <cmath>

// Problem constants
#define T_STEPS 16384
#define D_IN    257
#define H_DIM   512
#define O_DIM   257
#define G4      2048   // 4*H

typedef unsigned long long u64;

// Workspace layout (bytes):
//   [0, 8192)    : u64 msg[2][512]  (double-buffered self-validating h msgs)
//                  msg word i = (tag << 32) | float_bits(h[i])
//   [8192, ...)  : float x_gates[T][2048]
//   then         : float hs[T][512]
#define WS_XG_OFF     8192
#define WS_HS_OFF     (8192 + (size_t)T_STEPS * G4 * 4)

__device__ inline float fast_sigmoid(float x) {
    return 1.f / (1.f + __expf(-x));
}
__device__ inline float fast_tanh(float x) {
    float ax = fminf(fabsf(x), 15.f);
    float e  = __expf(2.f * ax);
    float t  = (e - 1.f) / (e + 1.f);
    return copysignf(t, x);
}
__device__ inline float dot4(float4 a, float4 b) {
    return a.x * b.x + a.y * b.y + a.z * b.z + a.w * b.w;
}

// Register pin: forbid rematerialization of weight loads inside the loop.
#define PIN4(v) asm volatile("" : "+v"(v.x), "+v"(v.y), "+v"(v.z), "+v"(v.w))

// ---------------------------------------------------------------------------
// Phase 1: x_gates = stft @ W_ih^T + bias  (R0's proven 64x64 tile version)
// ---------------------------------------------------------------------------
__global__ __launch_bounds__(256) void xgate_gemm(
    const float* __restrict__ stft, const float* __restrict__ W_ih,
    const float* __restrict__ b_ih, const float* __restrict__ b_hh,
    float* __restrict__ xg)
{
    const int tid = threadIdx.x;
    const int tx = tid & 15, ty = tid >> 4;
    const int j0 = blockIdx.x * 64;
    const int t0 = blockIdx.y * 64;

    __shared__ float s_a[64][17];
    __shared__ float s_b[64][17];

    float acc[4][4] = {};

    for (int k0 = 0; k0 < D_IN; k0 += 16) {
        #pragma unroll
        for (int l = 0; l < 4; ++l) {
            int idx = tid + l * 256;
            int r  = idx >> 4;
            int kk = idx & 15;
            int k  = k0 + kk;
            s_a[r][kk] = (k < D_IN) ? stft[(size_t)(t0 + r) * D_IN + k] : 0.f;
            s_b[r][kk] = (k < D_IN) ? W_ih[(size_t)(j0 + r) * D_IN + k] : 0.f;
        }
        __syncthreads();
        #pragma unroll
        for (int kk = 0; kk < 16; ++kk) {
            float a[4], b[4];
            #pragma unroll
            for (int r = 0; r < 4; ++r) a[r] = s_a[ty * 4 + r][kk];
            #pragma unroll
            for (int c = 0; c < 4; ++c) b[c] = s_b[tx * 4 + c][kk];
            #pragma unroll
            for (int r = 0; r < 4; ++r)
                #pragma unroll
                for (int c = 0; c < 4; ++c)
                    acc[r][c] += a[r] * b[c];
        }
        __syncthreads();
    }

    float bias[4];
    #pragma unroll
    for (int c = 0; c < 4; ++c) {
        int j = j0 + tx * 4 + c;
        bias[c] = b_ih[j] + b_hh[j];
    }
    #pragma unroll
    for (int r = 0; r < 4; ++r) {
        int t = t0 + ty * 4 + r;
        #pragma unroll
        for (int c = 0; c < 4; ++c) {
            xg[(size_t)t * G4 + j0 + tx * 4 + c] = acc[r][c] + bias[c];
        }
    }
}

// ---------------------------------------------------------------------------
// Phase 2: persistent sequential LSTM — R0's front half (coalesced poll +
// single lgkm-only barrier), NEW back half: FULL-ROW-PER-WAVE.
//
// R6 post-mortem: poll was already coalesced (32 req/line/round both ways);
// queueing theory dead; hop is latency physics (~1 MALL RT = 530cyc,
// calibrated by R6's +3.6ms for one extra serial trip). So attack the
// non-hop serial segments instead: R0 spent ~250-350cyc/step on the s_part
// LDS round trip + wave0-only serial tail (8 partial reads + sum + gather
// + activations) AFTER the barrier. Here wave w owns h-indices {2w,2w+1}
// end-to-end: all 4 gate rows over the FULL 512 cols (64 pinned weight
// VGPRs/lane, same total FLOPs), 6-stage shuffle fold (row r lands in
// lanes with l&7 -> exact-replicated sums), in-wave activations + c_state,
// direct 2-lane publish. s_part deleted; publish ~250cyc earlier.
//
// s_h double-buffered; reuse without trailing barrier is safe: wave w's
// write of s_h[b] at t+2 requires detect(t+2) <= 2-hop dependency chain
// that transitively requires EVERY wave of EVERY block to have published
// t+1, which (program order) is after their step-t reads of s_h[b].
// ---------------------------------------------------------------------------
__global__ __launch_bounds__(512, 1) void lstm_seq(
    const float* __restrict__ W_hh, const float* __restrict__ xg,
    float* __restrict__ hs, u64* __restrict__ msg)
{
    const int tid  = threadIdx.x;        // 0..511
    const int g    = blockIdx.x;         // 0..31
    const int w    = tid >> 6;           // wave id: owns h-indices {2w, 2w+1}
    const int lane = tid & 63;

    // Fold delivers row I(l) = ((l&1)<<2) | (l&2) | ((l>>2)&1)  (I = gate*2+jbit)
    const int gate = ((lane & 1) << 1) | ((lane >> 1) & 1);  // I>>1
    const int jbit = (lane >> 2) & 1;                        // I&1
    const int jloc = 2 * w + jbit;       // this lane's h-index within block

    // Weights: p[i] accumulates W_hh row (i>>1)*512 + (g*16 + 2w + (i&1)),
    // cols [8*lane, 8*lane+8). 16 float4 = 64 VGPRs, pinned.
    float4 wv[16];
    #pragma unroll
    for (int i = 0; i < 8; ++i) {
        size_t R = (size_t)(i >> 1) * H_DIM + (size_t)(g * 16 + 2 * w + (i & 1));
        const float4* p = (const float4*)(W_hh + R * H_DIM + 8 * lane);
        wv[2 * i]     = p[0];
        wv[2 * i + 1] = p[1];
    }
    #pragma unroll
    for (int i = 0; i < 16; ++i) PIN4(wv[i]);

    __shared__ float s_h[2][512];        // double-buffered staged h

    u64* slot0 = msg;
    u64* slot1 = msg + 512;

    float c_state = 0.f;                 // replicated: valid for this lane's jbit
    const int xoff = gate * H_DIM + g * 16 + jloc;  // xg offset of MY row

    for (int t = 0; t < T_STEPS; ++t) {
        const unsigned tagt = (unsigned)t;
        const int buf = t & 1;

        // Per-lane xg prefetch for MY row (8 lanes/address -> broadcast).
        float xv = __builtin_nontemporal_load(xg + (size_t)t * G4 + xoff);

        // Poll own msg word — R0's exact coalesced single-outstanding poll.
        u64* rp = (buf ? slot1 : slot0) + tid;
        u64 u;
        for (;;) {
            u = __hip_atomic_load(rp, __ATOMIC_RELAXED, __HIP_MEMORY_SCOPE_AGENT);
            if ((unsigned)(u >> 32) == tagt) break;
        }
        s_h[buf][tid] = __uint_as_float((unsigned)u);

        // lgkm-only barrier: staging visible to all waves; NO vmcnt drain.
        asm volatile("s_waitcnt lgkmcnt(0)\n\ts_barrier" ::: "memory");

        // Full-row partials: my 8 cols [8*lane, 8*lane+8) for all 8 rows.
        const float4* hv = (const float4*)(&s_h[buf][8 * lane]);
        float4 hA = hv[0], hB = hv[1];
        float p[8];
        #pragma unroll
        for (int i = 0; i < 8; ++i)
            p[i] = dot4(wv[2 * i], hA) + dot4(wv[2 * i + 1], hB);

        // 6-stage fold: rows -> lanes (stages 0-2), then full-width sum (3-5).
        float sum;
        {
            const bool b0 = lane & 1;
            float q[4];
            #pragma unroll
            for (int i = 0; i < 4; ++i) {
                float keep = b0 ? p[i + 4] : p[i];
                float send = b0 ? p[i]     : p[i + 4];
                q[i] = keep + __shfl_xor(send, 1, 64);
            }
            const bool b1 = lane & 2;
            float r2[2];
            #pragma unroll
            for (int i = 0; i < 2; ++i) {
                float keep = b1 ? q[i + 2] : q[i];
                float send = b1 ? q[i]     : q[i + 2];
                r2[i] = keep + __shfl_xor(send, 2, 64);
            }
            const bool b2 = lane & 4;
            float keep = b2 ? r2[1] : r2[0];
            float send = b2 ? r2[0] : r2[1];
            float s = keep + __shfl_xor(send, 4, 64);
            s += __shfl_xor(s, 8, 64);
            s += __shfl_xor(s, 16, 64);
            s += __shfl_xor(s, 32, 64);
            sum = s + xv;
        }

        // Activation for MY row; gather the 4 gates of MY jbit.
        float act = (gate == 2) ? fast_tanh(sum) : fast_sigmoid(sum);
        const int lbase = lane & ~3;     // gate G lives at bits l0=(G>>1), l1=(G&1)
        float iv = __shfl(act, lbase | 0, 64);   // G=0
        float fv = __shfl(act, lbase | 2, 64);   // G=1
        float gv = __shfl(act, lbase | 1, 64);   // G=2
        float ov = __shfl(act, lbase | 3, 64);   // G=3

        c_state = fv * c_state + iv * gv;        // exact-replicated per jbit
        float hn = ov * fast_tanh(c_state);

        // Direct in-wave publish: lanes 0 (jbit=0) and 4 (jbit=1).
        if (lane == 0 || lane == 4) {
            u64 m = ((u64)(tagt + 1) << 32) | (u64)__float_as_uint(hn);
            u64* wp = (((t + 1) & 1) ? slot1 : slot0) + (g * 16 + jloc);
            __hip_atomic_store(wp, m, __ATOMIC_RELAXED, __HIP_MEMORY_SCOPE_AGENT);
            __builtin_nontemporal_store(hn, hs + (size_t)t * H_DIM + g * 16 + jloc);
        }
        // No trailing barrier: s_h double-buffered; t+2 rewrite gated by the
        // 2-hop publish dependency chain (see header comment).
    }
}

// ---------------------------------------------------------------------------
// Phase 3: out = log_softmax(hs @ W_out^T + b_out)
// ---------------------------------------------------------------------------
__global__ __launch_bounds__(256) void out_softmax(
    const float* __restrict__ hs, const float* __restrict__ W_out,
    const float* __restrict__ b_out, float* __restrict__ out)
{
    const int tid = threadIdx.x;
    const int t0  = blockIdx.x * 16;

    __shared__ float s_w[257 * 33];
    __shared__ float s_hs[16 * 33];
    __shared__ float s_o[16 * 257];
    __shared__ float s_red[8];

    float acc[16] = {};
    float acc256 = 0.f;

    for (int k0 = 0; k0 < H_DIM; k0 += 32) {
        for (int idx = tid; idx < 257 * 32; idx += 256) {
            int row = idx >> 5, col = idx & 31;
            s_w[row * 33 + col] = W_out[(size_t)row * H_DIM + k0 + col];
        }
        for (int idx = tid; idx < 16 * 32; idx += 256) {
            int row = idx >> 5, col = idx & 31;
            s_hs[row * 33 + col] = hs[(size_t)(t0 + row) * H_DIM + k0 + col];
        }
        __syncthreads();
        #pragma unroll
        for (int kk = 0; kk < 32; ++kk) {
            float w = s_w[tid * 33 + kk];
            #pragma unroll
            for (int r = 0; r < 16; ++r)
                acc[r] += s_hs[r * 33 + kk] * w;
        }
        if (tid < 16) {
            #pragma unroll
            for (int kk = 0; kk < 32; ++kk)
                acc256 += s_w[256 * 33 + kk] * s_hs[tid * 33 + kk];
        }
        __syncthreads();
    }

    float bias_c = b_out[tid];
    #pragma unroll
    for (int r = 0; r < 16; ++r) s_o[r * 257 + tid] = acc[r] + bias_c;
    if (tid < 16) s_o[tid * 257 + 256] = acc256 + b_out[256];
    __syncthreads();

    const int lane = tid & 63, wid = tid >> 6;
    for (int r = 0; r < 16; ++r) {
        float v  = s_o[r * 257 + tid];
        float vx = (tid == 0) ? s_o[r * 257 + 256] : -INFINITY;
        float m = fmaxf(v, vx);
        #pragma unroll
        for (int off = 32; off > 0; off >>= 1) m = fmaxf(m, __shfl_xor(m, off, 64));
        if (lane == 0) s_red[wid] = m;
        __syncthreads();
        m = fmaxf(fmaxf(s_red[0], s_red[1]), fmaxf(s_red[2], s_red[3]));
        float e = expf(v - m) + ((tid == 0) ? expf(vx - m) : 0.f);
        #pragma unroll
        for (int off = 32; off > 0; off >>= 1) e += __shfl_xor(e, off, 64);
        if (lane == 0) s_red[4 + wid] = e;
        __syncthreads();
        float s = s_red[4] + s_red[5] + s_red[6] + s_red[7];
        float lg = logf(s) + m;
        out[(size_t)(t0 + r) * O_DIM + tid] = v - lg;
        if (tid == 0) out[(size_t)(t0 + r) * O_DIM + 256] = vx - lg;
    }
}

// ---------------------------------------------------------------------------
extern "C" void kernel_launch(void* const* d_in, const int* in_sizes, int n_in,
                              void* d_out, int out_size, void* d_ws, size_t ws_size,
                              hipStream_t stream) {
    (void)in_sizes; (void)n_in; (void)out_size; (void)ws_size;

    const float* stft  = (const float*)d_in[0];
    const float* W_ih  = (const float*)d_in[1];
    const float* W_hh  = (const float*)d_in[2];
    const float* b_ih  = (const float*)d_in[3];
    const float* b_hh  = (const float*)d_in[4];
    const float* W_out = (const float*)d_in[5];
    const float* b_out = (const float*)d_in[6];
    float* out = (float*)d_out;

    char* ws = (char*)d_ws;
    u64* msg  = (u64*)ws;
    float* xg = (float*)(ws + WS_XG_OFF);
    float* hs = (float*)(ws + WS_HS_OFF);

    // Zero both msg slots (tag 0 + h 0 is exactly the t=0 initial state).
    (void)hipMemsetAsync(ws, 0, 8192, stream);

    xgate_gemm<<<dim3(G4 / 64, T_STEPS / 64), 256, 0, stream>>>(
        stft, W_ih, b_ih, b_hh, xg);
    lstm_seq<<<32, 512, 0, stream>>>(W_hh, xg, hs, msg);
    out_softmax<<<T_STEPS / 16, 256, 0, stream>>>(hs, W_out, b_out, out);
}

// Round 8
// 23235.616 us; speedup vs baseline: 1.6436x; 1.6436x over previous
//
#include <hip/hip_runtime.h>
#include <cmath>

// Problem constants
#define T_STEPS 16384
#define D_IN    257
#define H_DIM   512
#define O_DIM   257
#define G4      2048   // 4*H

typedef unsigned long long u64;

// Workspace layout (bytes):
//   [0, 8192)    : u64 msg[2][512]  (double-buffered self-validating h msgs)
//                  msg word i = (tag << 32) | float_bits(h[i])
//   [8192, ...)  : float x_gates[T][2048]
//   then         : float hs[T][512]
#define WS_XG_OFF     8192
#define WS_HS_OFF     (8192 + (size_t)T_STEPS * G4 * 4)

__device__ inline float fast_sigmoid(float x) {
    return 1.f / (1.f + __expf(-x));
}
__device__ inline float fast_tanh(float x) {
    float ax = fminf(fabsf(x), 15.f);
    float e  = __expf(2.f * ax);
    float t  = (e - 1.f) / (e + 1.f);
    return copysignf(t, x);
}
__device__ inline float dot4(float4 a, float4 b) {
    return a.x * b.x + a.y * b.y + a.z * b.z + a.w * b.w;
}

// Register pin: marks the value as asm-modified so the compiler cannot
// legally rematerialize the (const __restrict__) weight loads inside the
// loop — forces true register residency across the K-loop's memory clobbers.
#define PIN4(v) asm volatile("" : "+v"(v.x), "+v"(v.y), "+v"(v.z), "+v"(v.w))

// ---------------------------------------------------------------------------
// Phase 1: x_gates = stft @ W_ih^T + bias  (R0's proven 64x64 tile version)
// ---------------------------------------------------------------------------
__global__ __launch_bounds__(256) void xgate_gemm(
    const float* __restrict__ stft, const float* __restrict__ W_ih,
    const float* __restrict__ b_ih, const float* __restrict__ b_hh,
    float* __restrict__ xg)
{
    const int tid = threadIdx.x;
    const int tx = tid & 15, ty = tid >> 4;
    const int j0 = blockIdx.x * 64;
    const int t0 = blockIdx.y * 64;

    __shared__ float s_a[64][17];
    __shared__ float s_b[64][17];

    float acc[4][4] = {};

    for (int k0 = 0; k0 < D_IN; k0 += 16) {
        #pragma unroll
        for (int l = 0; l < 4; ++l) {
            int idx = tid + l * 256;
            int r  = idx >> 4;
            int kk = idx & 15;
            int k  = k0 + kk;
            s_a[r][kk] = (k < D_IN) ? stft[(size_t)(t0 + r) * D_IN + k] : 0.f;
            s_b[r][kk] = (k < D_IN) ? W_ih[(size_t)(j0 + r) * D_IN + k] : 0.f;
        }
        __syncthreads();
        #pragma unroll
        for (int kk = 0; kk < 16; ++kk) {
            float a[4], b[4];
            #pragma unroll
            for (int r = 0; r < 4; ++r) a[r] = s_a[ty * 4 + r][kk];
            #pragma unroll
            for (int c = 0; c < 4; ++c) b[c] = s_b[tx * 4 + c][kk];
            #pragma unroll
            for (int r = 0; r < 4; ++r)
                #pragma unroll
                for (int c = 0; c < 4; ++c)
                    acc[r][c] += a[r] * b[c];
        }
        __syncthreads();
    }

    float bias[4];
    #pragma unroll
    for (int c = 0; c < 4; ++c) {
        int j = j0 + tx * 4 + c;
        bias[c] = b_ih[j] + b_hh[j];
    }
    #pragma unroll
    for (int r = 0; r < 4; ++r) {
        int t = t0 + ty * 4 + r;
        #pragma unroll
        for (int c = 0; c < 4; ++c) {
            xg[(size_t)t * G4 + j0 + tx * 4 + c] = acc[r][c] + bias[c];
        }
    }
}

// ---------------------------------------------------------------------------
// Phase 2: persistent sequential LSTM — EXACT R0 structure (best measured:
// coalesced single-outstanding poll, one lgkm-only barrier, s_part + wave0
// tail, wave-coalesced 16-word publish), plus two surgical trims:
//
// (1) xg PREFETCH ONE STEP AHEAD. In R0 the xv load was issued immediately
//     before the poll; the poll's compiler-emitted vmcnt(0) made wave0's
//     FIRST tag sample wait on a cold HBM load (~600-900cyc) instead of
//     ~530. Since wave0's detect gates the tail and the barrier waits on
//     max-of-waves, that was pure critical-path loss. Now xv for t+1 is
//     issued right after detect(t) (~2500cyc before use), and an asm pin
//     BEFORE the poll forces its (instant) waitcnt, so neither the poll
//     nor the tail ever waits on xg.
//
// (2) ACTIVATE-BEFORE-GATHER in the tail. Each lane activates its OWN row
//     (row = gate*16 + t_j; sigmoid/tanh computed with ILP and selected),
//     THEN gathers the 4 activated gates. Post-gather dependent chain
//     shrinks from [4 transcendentals + c-update + tanh] to
//     [2 FMA + tanh] (~130cyc off the critical path).
//
// R7 lesson kept: publish remains ONE wave-coalesced line store (msg word
// i = (tag<<32)|bits(h_i), 16 lanes, one 128B line per producer).
// ---------------------------------------------------------------------------
__global__ __launch_bounds__(512, 1) void lstm_seq(
    const float* __restrict__ W_hh, const float* __restrict__ xg,
    float* __restrict__ hs, u64* __restrict__ msg)
{
    const int tid  = threadIdx.x;        // 0..511
    const int g    = blockIdx.x;         // 0..31
    const int w    = tid >> 6;           // wave id = col chunk 0..7
    const int lane = tid & 63;
    const int j    = lane >> 2;          // 0..15 h-index within block
    const int c    = lane & 3;           // 0..3 16-col sub-chunk
    const int colb = w * 64 + c * 16;    // this lane's col base

    // Weights: all 4 gate rows of h-index (g*16+j), 16 cols each.
    const float* wbase = W_hh + (size_t)(g * 16 + j) * H_DIM + colb;
    const size_t gstride = (size_t)H_DIM * H_DIM;  // 512*512 between gates
    float4 wA0, wA1, wA2, wA3, wB0, wB1, wB2, wB3;
    float4 wC0, wC1, wC2, wC3, wD0, wD1, wD2, wD3;
    {
        const float4* p0 = (const float4*)(wbase);
        const float4* p1 = (const float4*)(wbase + gstride);
        const float4* p2 = (const float4*)(wbase + 2 * gstride);
        const float4* p3 = (const float4*)(wbase + 3 * gstride);
        wA0 = p0[0]; wA1 = p0[1]; wA2 = p0[2]; wA3 = p0[3];
        wB0 = p1[0]; wB1 = p1[1]; wB2 = p1[2]; wB3 = p1[3];
        wC0 = p2[0]; wC1 = p2[1]; wC2 = p2[2]; wC3 = p2[3];
        wD0 = p3[0]; wD1 = p3[1]; wD2 = p3[2]; wD3 = p3[3];
    }
    // Pin: forbid rematerialization — weights stay in VGPRs for the whole loop.
    PIN4(wA0); PIN4(wA1); PIN4(wA2); PIN4(wA3);
    PIN4(wB0); PIN4(wB1); PIN4(wB2); PIN4(wB3);
    PIN4(wC0); PIN4(wC1); PIN4(wC2); PIN4(wC3);
    PIN4(wD0); PIN4(wD1); PIN4(wD2); PIN4(wD3);

    __shared__ float s_h[512];           // wave w stages+reads [64w,64w+64) only
    __shared__ float s_part[2][512];     // [t&1][w*64 + c*16 + j]

    u64* slot0 = msg;
    u64* slot1 = msg + 512;

    float c_state = 0.f;                 // wave0: state for j'=lane&15 (x4 repl)
    const int t_j = lane & 15;           // wave0 tail: h-index within block
    const int gate = lane >> 4;          // wave0 tail: gate of MY row

    // Wave0: xg prefetch ONE STEP AHEAD (t=0 issued here).
    float xv_next = 0.f;
    if (w == 0)
        xv_next = __builtin_nontemporal_load(
            xg + (size_t)0 * G4 + gate * H_DIM + g * 16 + t_j);

    for (int t = 0; t < T_STEPS; ++t) {
        const unsigned tagt = (unsigned)t;
        const int buf = t & 1;

        // Materialize last step's prefetch BEFORE the poll: the vmcnt wait
        // lands here (instant — issued ~2500cyc ago), not inside the poll
        // and not in the tail.
        float xv = 0.f;
        if (w == 0) {
            xv = xv_next;
            asm volatile("" : "+v"(xv));
        }

        // Poll own single message word: tag==t validates payload in-load.
        // Single-outstanding, wave-coalesced (32 req/line/round) — proven
        // best of 7 variants (R1,R2,R3,R4,R6,R7 all regressed).
        u64* rp = (buf ? slot1 : slot0) + tid;
        u64 u;
        for (;;) {
            u = __hip_atomic_load(rp, __ATOMIC_RELAXED, __HIP_MEMORY_SCOPE_AGENT);
            if ((unsigned)(u >> 32) == tagt) break;
        }

        // Issue NEXT step's xg prefetch now — hides its HBM latency under
        // compute + barrier + tail of this step.
        if (w == 0) {
            int tn = (t + 1 < T_STEPS) ? t + 1 : t;
            xv_next = __builtin_nontemporal_load(
                xg + (size_t)tn * G4 + gate * H_DIM + g * 16 + t_j);
        }

        // Intra-wave h staging: wave w only touches its own 64-word region.
        s_h[tid] = __uint_as_float((unsigned)u);

        // h slice for this lane: 16 floats (4x b128, broadcast across j).
        const float4* hv = (const float4*)(s_h + colb);
        float4 h0 = hv[0], h1 = hv[1], h2 = hv[2], h3 = hv[3];

        // 4 gate partials over this lane's 16 cols (weights in registers).
        float p0 = dot4(wA0, h0) + dot4(wA1, h1) + dot4(wA2, h2) + dot4(wA3, h3);
        float p1 = dot4(wB0, h0) + dot4(wB1, h1) + dot4(wB2, h2) + dot4(wB3, h3);
        float p2 = dot4(wC0, h0) + dot4(wC1, h1) + dot4(wC2, h2) + dot4(wC3, h3);
        float p3 = dot4(wD0, h0) + dot4(wD1, h1) + dot4(wD2, h2) + dot4(wD3, h3);

        // Exchange-half butterfly over the 4 c-lanes: lane c ends with the
        // full 64-col sum of gate c. 3 shuffles total.
        const bool lo2 = (c < 2);
        float a0 = (lo2 ? p0 : p2) + __shfl_xor(lo2 ? p2 : p0, 2, 64);
        float a1 = (lo2 ? p1 : p3) + __shfl_xor(lo2 ? p3 : p1, 2, 64);
        const bool ev = ((c & 1) == 0);
        float fin = (ev ? a0 : a1) + __shfl_xor(ev ? a1 : a0, 1, 64);

        // Write this wave's partial for row (gate=c, j): 2-way banks = free.
        s_part[buf][w * 64 + c * 16 + j] = fin;

        // lgkm-only barrier: LDS writes visible; NO vmcnt drain (publish
        // stores and xg prefetch stay in flight).
        asm volatile("s_waitcnt lgkmcnt(0)\n\ts_barrier" ::: "memory");

        if (w == 0) {
            // Sum the 8 per-wave partials for this lane's row (r = lane).
            const float* pp = &s_part[buf][0];
            float sum = xv;
            #pragma unroll
            for (int k = 0; k < 8; ++k) sum += pp[k * 64 + lane];

            // Activate MY row first (sigmoid/tanh overlap via ILP, then
            // select) — the gather then delivers ACTIVATED gates, leaving
            // only [2 FMA + tanh] on the dependent chain.
            float sg = fast_sigmoid(sum);
            float th = fast_tanh(sum);
            float act = (gate == 2) ? th : sg;

            float iv = __shfl(act, t_j + 0,  64);
            float fv = __shfl(act, t_j + 16, 64);
            float gv = __shfl(act, t_j + 32, 64);
            float ov = __shfl(act, t_j + 48, 64);

            c_state = fv * c_state + iv * gv;     // identical on the 4 gate-lanes
            float hn = ov * fast_tanh(c_state);

            if (lane < 16) {                      // t_j == lane here
                // Publish FIRST (critical word into the fabric before the
                // bulk hs stream), one coalesced 128B line per producer.
                u64 m = ((u64)(tagt + 1) << 32) | (u64)__float_as_uint(hn);
                u64* wp = (((t + 1) & 1) ? slot1 : slot0) + (g * 16 + lane);
                __hip_atomic_store(wp, m, __ATOMIC_RELAXED, __HIP_MEMORY_SCOPE_AGENT);
                __builtin_nontemporal_store(hn, hs + (size_t)t * H_DIM + g * 16 + lane);
            }
        }
        // No trailing barrier: s_h is intra-wave; s_part double-buffered —
        // its re-write at t+2 is gated by the barrier at t+1, which wave 0
        // only reaches after finishing its reads of s_part[t&1].
    }
}

// ---------------------------------------------------------------------------
// Phase 3: out = log_softmax(hs @ W_out^T + b_out)
// ---------------------------------------------------------------------------
__global__ __launch_bounds__(256) void out_softmax(
    const float* __restrict__ hs, const float* __restrict__ W_out,
    const float* __restrict__ b_out, float* __restrict__ out)
{
    const int tid = threadIdx.x;
    const int t0  = blockIdx.x * 16;

    __shared__ float s_w[257 * 33];
    __shared__ float s_hs[16 * 33];
    __shared__ float s_o[16 * 257];
    __shared__ float s_red[8];

    float acc[16] = {};
    float acc256 = 0.f;

    for (int k0 = 0; k0 < H_DIM; k0 += 32) {
        for (int idx = tid; idx < 257 * 32; idx += 256) {
            int row = idx >> 5, col = idx & 31;
            s_w[row * 33 + col] = W_out[(size_t)row * H_DIM + k0 + col];
        }
        for (int idx = tid; idx < 16 * 32; idx += 256) {
            int row = idx >> 5, col = idx & 31;
            s_hs[row * 33 + col] = hs[(size_t)(t0 + row) * H_DIM + k0 + col];
        }
        __syncthreads();
        #pragma unroll
        for (int kk = 0; kk < 32; ++kk) {
            float w = s_w[tid * 33 + kk];
            #pragma unroll
            for (int r = 0; r < 16; ++r)
                acc[r] += s_hs[r * 33 + kk] * w;
        }
        if (tid < 16) {
            #pragma unroll
            for (int kk = 0; kk < 32; ++kk)
                acc256 += s_w[256 * 33 + kk] * s_hs[tid * 33 + kk];
        }
        __syncthreads();
    }

    float bias_c = b_out[tid];
    #pragma unroll
    for (int r = 0; r < 16; ++r) s_o[r * 257 + tid] = acc[r] + bias_c;
    if (tid < 16) s_o[tid * 257 + 256] = acc256 + b_out[256];
    __syncthreads();

    const int lane = tid & 63, wid = tid >> 6;
    for (int r = 0; r < 16; ++r) {
        float v  = s_o[r * 257 + tid];
        float vx = (tid == 0) ? s_o[r * 257 + 256] : -INFINITY;
        float m = fmaxf(v, vx);
        #pragma unroll
        for (int off = 32; off > 0; off >>= 1) m = fmaxf(m, __shfl_xor(m, off, 64));
        if (lane == 0) s_red[wid] = m;
        __syncthreads();
        m = fmaxf(fmaxf(s_red[0], s_red[1]), fmaxf(s_red[2], s_red[3]));
        float e = expf(v - m) + ((tid == 0) ? expf(vx - m) : 0.f);
        #pragma unroll
        for (int off = 32; off > 0; off >>= 1) e += __shfl_xor(e, off, 64);
        if (lane == 0) s_red[4 + wid] = e;
        __syncthreads();
        float s = s_red[4] + s_red[5] + s_red[6] + s_red[7];
        float lg = logf(s) + m;
        out[(size_t)(t0 + r) * O_DIM + tid] = v - lg;
        if (tid == 0) out[(size_t)(t0 + r) * O_DIM + 256] = vx - lg;
    }
}

// ---------------------------------------------------------------------------
extern "C" void kernel_launch(void* const* d_in, const int* in_sizes, int n_in,
                              void* d_out, int out_size, void* d_ws, size_t ws_size,
                              hipStream_t stream) {
    (void)in_sizes; (void)n_in; (void)out_size; (void)ws_size;

    const float* stft  = (const float*)d_in[0];
    const float* W_ih  = (const float*)d_in[1];
    const float* W_hh  = (const float*)d_in[2];
    const float* b_ih  = (const float*)d_in[3];
    const float* b_hh  = (const float*)d_in[4];
    const float* W_out = (const float*)d_in[5];
    const float* b_out = (const float*)d_in[6];
    float* out = (float*)d_out;

    char* ws = (char*)d_ws;
    u64* msg  = (u64*)ws;
    float* xg = (float*)(ws + WS_XG_OFF);
    float* hs = (float*)(ws + WS_HS_OFF);

    // Zero both msg slots (tag 0 + h 0 is exactly the t=0 initial state).
    (void)hipMemsetAsync(ws, 0, 8192, stream);

    xgate_gemm<<<dim3(G4 / 64, T_STEPS / 64), 256, 0, stream>>>(
        stft, W_ih, b_ih, b_hh, xg);
    lstm_seq<<<32, 512, 0, stream>>>(W_hh, xg, hs, msg);
    out_softmax<<<T_STEPS / 16, 256, 0, stream>>>(hs, W_out, b_out, out);
}